// Round 1
// baseline (513.228 us; speedup 1.0000x reference)
//
#include <hip/hip_runtime.h>

#define NN 6000
#define FF 128
#define EE 144000

typedef __attribute__((ext_vector_type(8))) short bf16x8;
typedef __attribute__((ext_vector_type(4))) float f32x4;

__device__ __forceinline__ unsigned short f2bf(float f) {
  unsigned int u = __float_as_uint(f);
  u += 0x7FFF + ((u >> 16) & 1);
  return (unsigned short)(u >> 16);
}
__device__ __forceinline__ float lexp(float v) {
  v = v > 0.f ? v : 0.2f * v;   // leaky_relu(0.2) then exp
  return __expf(v);
}

// ---- preprocessing -------------------------------------------------------
__global__ void k_deg(const int* __restrict__ ei, const float* __restrict__ ew,
                      float* __restrict__ deg, int* __restrict__ cnt,
                      float* __restrict__ easum) {
  int e = blockIdx.x * 256 + threadIdx.x;
  float w = 0.f;
  if (e < EE) {
    int c = ei[EE + e];
    w = ew[e];
    atomicAdd(deg + c, w);
    atomicAdd(cnt + c, 1);
  }
  __shared__ float red[256];
  red[threadIdx.x] = w;
  __syncthreads();
  for (int off = 128; off > 0; off >>= 1) {
    if (threadIdx.x < off) red[threadIdx.x] += red[threadIdx.x + off];
    __syncthreads();
  }
  if (threadIdx.x == 0) atomicAdd(easum, red[0]);
}

__global__ void k_dinv(const float* __restrict__ deg, float* __restrict__ dinv,
                       const float* __restrict__ We, const float* __restrict__ aedge,
                       float* __restrict__ wd) {
  int i = blockIdx.x * 256 + threadIdx.x;
  if (i < NN) dinv[i] = rsqrtf(deg[i] + 1.0f);   // +1 = self-loop weight
  if (blockIdx.x == 0) {
    __shared__ float red[512];
    int t = threadIdx.x;
    red[t] = We[t] * aedge[t];
    red[t + 256] = We[t + 256] * aedge[t + 256];
    __syncthreads();
    for (int off = 64; off > 0; off >>= 1) {
      int ch = t >> 7, idx = t & 127;
      if (idx < off) {
        red[ch * 128 + idx] += red[ch * 128 + idx + off];
        red[(2 + ch) * 128 + idx] += red[(2 + ch) * 128 + idx + off];
      }
      __syncthreads();
    }
    if (t < 4) wd[t] = red[t * 128];
  }
}

__global__ void k_scan(const int* __restrict__ cnt, int* __restrict__ rp, int n) {
  __shared__ int buf[1024];
  __shared__ int carry_s;
  int t = threadIdx.x;
  if (t == 0) carry_s = 0;
  __syncthreads();
  for (int base = 0; base < n; base += 1024) {
    int v = (base + t < n) ? cnt[base + t] : 0;
    buf[t] = v;
    __syncthreads();
    for (int off = 1; off < 1024; off <<= 1) {
      int x = (t >= off) ? buf[t - off] : 0;
      __syncthreads();
      buf[t] += x;
      __syncthreads();
    }
    int carry = carry_s;
    if (base + t < n) rp[base + t + 1] = carry + buf[t];
    __syncthreads();
    if (t == 1023) carry_s = carry + buf[1023];
    __syncthreads();
  }
  if (t == 0) rp[0] = 0;
}

__global__ void k_fill(const int* __restrict__ ei, const float* __restrict__ ew,
                       const int* __restrict__ rp, int* __restrict__ cursor,
                       const float* __restrict__ dinv,
                       int* __restrict__ sr, int* __restrict__ sc,
                       float* __restrict__ swt, float* __restrict__ snorm) {
  int e = blockIdx.x * 256 + threadIdx.x;
  if (e >= EE) return;
  int r = ei[e], c = ei[EE + e];
  float w = ew[e];
  int pos = rp[c] + atomicAdd(cursor + c, 1);
  sr[pos] = r;
  sc[pos] = c;
  swt[pos] = w;
  snorm[pos] = dinv[r] * w * dinv[c];
}

// ---- weight repacks ------------------------------------------------------
__global__ void k_bcat(const float* __restrict__ Wg, const float* __restrict__ WL,
                       float* __restrict__ Bcat) {
  int i = blockIdx.x * 256 + threadIdx.x;
  if (i >= 128 * 640) return;
  int k = i / 640, j = i % 640;
  Bcat[i] = (j < 512) ? Wg[k * 512 + j] : WL[k * 128 + (j - 512)];
}
__global__ void k_bc(const float* __restrict__ cW, float* __restrict__ Bc) {
  int i = blockIdx.x * 256 + threadIdx.x;
  if (i >= 256 * 128) return;
  int k = i / 128, o = i % 128;
  Bc[i] = cW[o * 256 + k];
}

// ---- generic fp32 GEMM: C[M,N] = A[M,K]@B[K,N]  (N%64==0, K%32==0) -------
__global__ __launch_bounds__(256) void k_gemm(
    const float* __restrict__ A, int lda,
    const float* __restrict__ B, int ldb,
    float* __restrict__ C, int ldc,
    int M, int N, int K,
    const float* __restrict__ bias,
    unsigned short* __restrict__ Cb) {
  __shared__ float As[32][68];   // [k][row], padded: 68*4B keeps 16B row align
  __shared__ float Bs[32][64];   // [k][col]
  int t = threadIdx.x;
  int tx = t & 15, ty = t >> 4;
  int n0 = blockIdx.x * 64;
  int r0 = blockIdx.y * 64;
  float acc[4][4] = {};
  for (int kc = 0; kc < K; kc += 32) {
#pragma unroll
    for (int i = 0; i < 2; ++i) {
      int idx = t + i * 256;
      int row = idx >> 3, c4 = idx & 7;
      float4 v = {0.f, 0.f, 0.f, 0.f};
      if (r0 + row < M)
        v = *reinterpret_cast<const float4*>(A + (size_t)(r0 + row) * lda + kc + c4 * 4);
      As[c4 * 4 + 0][row] = v.x;
      As[c4 * 4 + 1][row] = v.y;
      As[c4 * 4 + 2][row] = v.z;
      As[c4 * 4 + 3][row] = v.w;
    }
#pragma unroll
    for (int i = 0; i < 2; ++i) {
      int idx = t + i * 256;
      int kk = idx >> 4, c4 = idx & 15;
      float4 v = *reinterpret_cast<const float4*>(B + (size_t)(kc + kk) * ldb + n0 + c4 * 4);
      *reinterpret_cast<float4*>(&Bs[kk][c4 * 4]) = v;
    }
    __syncthreads();
#pragma unroll 8
    for (int kk = 0; kk < 32; ++kk) {
      float4 av = *reinterpret_cast<const float4*>(&As[kk][ty * 4]);
      float4 bv = *reinterpret_cast<const float4*>(&Bs[kk][tx * 4]);
      float ar[4] = {av.x, av.y, av.z, av.w};
      float br[4] = {bv.x, bv.y, bv.z, bv.w};
#pragma unroll
      for (int i = 0; i < 4; ++i)
#pragma unroll
        for (int j = 0; j < 4; ++j) acc[i][j] = fmaf(ar[i], br[j], acc[i][j]);
    }
    __syncthreads();
  }
#pragma unroll
  for (int i = 0; i < 4; ++i) {
    int row = r0 + ty * 4 + i;
    if (row < M) {
#pragma unroll
      for (int j = 0; j < 4; ++j) {
        int col = n0 + tx * 4 + j;
        float v = acc[i][j] + (bias ? bias[col] : 0.f);
        C[(size_t)row * ldc + col] = v;
        if (Cb) Cb[(size_t)row * ldc + col] = f2bf(v);
      }
    }
  }
}

// ---- per-node, per-head attention pre-dots s,d ---------------------------
__global__ __launch_bounds__(256) void k_sd(const float* __restrict__ hbuf,
                                            const float* __restrict__ asrc,
                                            const float* __restrict__ adst,
                                            float* __restrict__ s, float* __restrict__ d) {
  int n = blockIdx.x;
  int t = threadIdx.x;
  int h = t >> 6, lane = t & 63;
  const float* hr = hbuf + (size_t)n * 640 + h * 128 + lane * 2;
  const float* as = asrc + h * 128 + lane * 2;
  const float* ad = adst + h * 128 + lane * 2;
  float e0 = hr[0], e1 = hr[1];
  float ps = e0 * as[0] + e1 * as[1];
  float pd = e0 * ad[0] + e1 * ad[1];
  for (int off = 32; off > 0; off >>= 1) {
    ps += __shfl_down(ps, off);
    pd += __shfl_down(pd, off);
  }
  if (lane == 0) { s[n * 4 + h] = ps; d[n * 4 + h] = pd; }
}

// ---- per-edge exp(leaky(logit)) -----------------------------------------
__global__ void k_p(const int* __restrict__ sr, const int* __restrict__ sc,
                    const float* __restrict__ swt,
                    const float* __restrict__ s, const float* __restrict__ d,
                    const float* __restrict__ wd, float* __restrict__ p4) {
  int e = blockIdx.x * 256 + threadIdx.x;
  if (e >= EE) return;
  int r = sr[e], c = sc[e];
  float ea = swt[e];
  float4 sv = *reinterpret_cast<const float4*>(s + r * 4);
  float4 dv = *reinterpret_cast<const float4*>(d + c * 4);
  float4 w4 = *reinterpret_cast<const float4*>(wd);
  float4 o;
  o.x = lexp(sv.x + dv.x + ea * w4.x);
  o.y = lexp(sv.y + dv.y + ea * w4.y);
  o.z = lexp(sv.z + dv.z + ea * w4.z);
  o.w = lexp(sv.w + dv.w + ea * w4.w);
  *reinterpret_cast<float4*>(p4 + (size_t)e * 4) = o;
}

// ---- fused GCN+GAT aggregate + combine + relu ----------------------------
__global__ __launch_bounds__(128) void k_agg(
    const int* __restrict__ rp, const int* __restrict__ sr,
    const float* __restrict__ snorm, const float* __restrict__ p4,
    const float* __restrict__ hbuf,
    const float* __restrict__ s, const float* __restrict__ d,
    const float* __restrict__ wd, const float* __restrict__ easum,
    const float* __restrict__ dinv,
    const float* __restrict__ gcnb, const float* __restrict__ gatb,
    float* __restrict__ xcat, int colOff) {
  int n = blockIdx.x;
  int c = threadIdx.x;
  float eam = easum[0] * (1.f / (float)EE);
  float4 w4 = *reinterpret_cast<const float4*>(wd);
  float4 sn = *reinterpret_cast<const float4*>(s + n * 4);
  float4 dn = *reinterpret_cast<const float4*>(d + n * 4);
  // self-loop (r = n, edge attr = mean(ew), gcn w = 1)
  float p0 = lexp(sn.x + dn.x + eam * w4.x);
  float p1 = lexp(sn.y + dn.y + eam * w4.y);
  float p2 = lexp(sn.z + dn.z + eam * w4.z);
  float p3 = lexp(sn.w + dn.w + eam * w4.w);
  const float* hn = hbuf + (size_t)n * 640;
  float a0 = p0 * hn[c], a1 = p1 * hn[128 + c], a2 = p2 * hn[256 + c], a3 = p3 * hn[384 + c];
  float dv = dinv[n];
  float ag = dv * dv * hn[512 + c];
  float d0 = p0, d1 = p1, d2 = p2, d3 = p3;
  int beg = rp[n], end = rp[n + 1];
  for (int pos = beg; pos < end; ++pos) {
    int r = sr[pos];
    float nr = snorm[pos];
    float4 pv = *reinterpret_cast<const float4*>(p4 + (size_t)pos * 4);
    const float* hr = hbuf + (size_t)r * 640;
    a0 += pv.x * hr[c];
    a1 += pv.y * hr[128 + c];
    a2 += pv.z * hr[256 + c];
    a3 += pv.w * hr[384 + c];
    ag += nr * hr[512 + c];
    d0 += pv.x; d1 += pv.y; d2 += pv.z; d3 += pv.w;
  }
  float gat = 0.25f * (a0 / d0 + a1 / d1 + a2 / d2 + a3 / d3);
  float l = ag + gcnb[c] + gat + gatb[c];
  xcat[(size_t)n * 256 + colOff + c] = fmaxf(0.5f * l, 0.f);
}

// ---- final MFMA: C[i,j] = sum_k drug[i,k]*dis[j,k] -----------------------
__global__ __launch_bounds__(256) void k_final(const unsigned short* __restrict__ Ab,
                                               const unsigned short* __restrict__ Bb,
                                               float* __restrict__ C) {
  int wave = threadIdx.x >> 6;
  int lane = threadIdx.x & 63;
  int wm = wave >> 1, wn = wave & 1;
  int m0 = blockIdx.y * 128 + wm * 64;
  int n0 = blockIdx.x * 128 + wn * 64;
  int lr = lane & 15;
  int lg = lane >> 4;
  f32x4 acc[4][4] = {};
#pragma unroll
  for (int ks = 0; ks < 4; ++ks) {
    int kcol = ks * 32 + lg * 8;
    bf16x8 a[4], b[4];
#pragma unroll
    for (int mt = 0; mt < 4; ++mt) {
      int row = m0 + mt * 16 + lr;
      bf16x8 v = {};
      if (row < NN) v = *reinterpret_cast<const bf16x8*>(Ab + (size_t)row * 128 + kcol);
      a[mt] = v;
    }
#pragma unroll
    for (int nt = 0; nt < 4; ++nt) {
      int rb = n0 + nt * 16 + lr;
      bf16x8 v = {};
      if (rb < NN) v = *reinterpret_cast<const bf16x8*>(Bb + (size_t)rb * 128 + kcol);
      b[nt] = v;
    }
#pragma unroll
    for (int mt = 0; mt < 4; ++mt)
#pragma unroll
      for (int nt = 0; nt < 4; ++nt)
        acc[mt][nt] = __builtin_amdgcn_mfma_f32_16x16x32_bf16(a[mt], b[nt], acc[mt][nt], 0, 0, 0);
  }
#pragma unroll
  for (int mt = 0; mt < 4; ++mt)
#pragma unroll
    for (int nt = 0; nt < 4; ++nt)
#pragma unroll
      for (int r = 0; r < 4; ++r) {
        int row = m0 + mt * 16 + lg * 4 + r;
        int col = n0 + nt * 16 + lr;
        if (row < NN && col < NN) C[(size_t)row * NN + col] = acc[mt][nt][r];
      }
}

// ==========================================================================
extern "C" void kernel_launch(void* const* d_in, const int* in_sizes, int n_in,
                              void* d_out, int out_size, void* d_ws, size_t ws_size,
                              hipStream_t stream) {
  const int N = NN, E = EE;
  char* wsp = (char*)d_ws;
  size_t off = 0;
  auto alloc = [&](size_t bytes) -> char* {
    char* ptr = wsp + off;
    off += (bytes + 255) & ~(size_t)255;
    return ptr;
  };
  // zero-region (one memset): deg, cnt, cursor, easum
  float* deg = (float*)alloc(N * 4);
  int* cnt = (int*)alloc(N * 4);
  int* cursor = (int*)alloc(N * 4);
  float* easum = (float*)alloc(256);
  size_t zero_bytes = (size_t)((char*)easum - (char*)deg) + 256;
  float* dinv = (float*)alloc(N * 4);
  int* rp = (int*)alloc((N + 1) * 4);
  float* wd = (float*)alloc(256);
  int* sr = (int*)alloc((size_t)E * 4);
  int* sc = (int*)alloc((size_t)E * 4);
  float* swt = (float*)alloc((size_t)E * 4);
  float* snorm = (float*)alloc((size_t)E * 4);
  float* Bcat = (float*)alloc((size_t)128 * 640 * 4);
  float* Bc = (float*)alloc((size_t)256 * 128 * 4);
  float* hbuf = (float*)alloc((size_t)N * 640 * 4);
  float* sbuf = (float*)alloc((size_t)N * 4 * 4);
  float* dbuf = (float*)alloc((size_t)N * 4 * 4);
  float* p4 = (float*)alloc((size_t)E * 4 * 4);
  float* xcat = (float*)alloc((size_t)N * 256 * 4);
  unsigned short* disb = (unsigned short*)alloc((size_t)N * 128 * 2);
  unsigned short* drugb = (unsigned short*)alloc((size_t)N * 128 * 2);
  if (off > ws_size) return;  // fail loud (wrong output) rather than corrupt

  float* out = (float*)d_out;
  float* fea_dis = out + (size_t)36000000;
  float* fea_drug = out + (size_t)36768000;

  auto branch = [&](const float* x, const int* ei, const float* ew,
                    const float* g1W, const float* g1b, const float* g2W, const float* g2b,
                    const float* gW, const float* gas, const float* gad,
                    const float* gWe, const float* gae, const float* gb,
                    const float* cW, const float* cb,
                    float* fea_out, unsigned short* feab) {
    hipMemsetAsync(deg, 0, zero_bytes, stream);
    k_deg<<<(E + 255) / 256, 256, 0, stream>>>(ei, ew, deg, cnt, easum);
    k_dinv<<<(N + 255) / 256, 256, 0, stream>>>(deg, dinv, gWe, gae, wd);
    k_scan<<<1, 1024, 0, stream>>>(cnt, rp, N);
    k_fill<<<(E + 255) / 256, 256, 0, stream>>>(ei, ew, rp, cursor, dinv, sr, sc, swt, snorm);
    for (int L = 0; L < 2; ++L) {
      const float* WL = L ? g2W : g1W;
      const float* bL = L ? g2b : g1b;
      k_bcat<<<(128 * 640 + 255) / 256, 256, 0, stream>>>(gW, WL, Bcat);
      const float* A = L ? xcat : x;
      int lda = L ? 256 : 128;
      k_gemm<<<dim3(10, 94), 256, 0, stream>>>(A, lda, Bcat, 640, hbuf, 640,
                                               N, 640, 128, nullptr, nullptr);
      k_sd<<<N, 256, 0, stream>>>(hbuf, gas, gad, sbuf, dbuf);
      k_p<<<(E + 255) / 256, 256, 0, stream>>>(sr, sc, swt, sbuf, dbuf, wd, p4);
      k_agg<<<N, 128, 0, stream>>>(rp, sr, snorm, p4, hbuf, sbuf, dbuf, wd,
                                   easum, dinv, bL, gb, xcat, L * 128);
    }
    k_bc<<<(256 * 128 + 255) / 256, 256, 0, stream>>>(cW, Bc);
    k_gemm<<<dim3(2, 94), 256, 0, stream>>>(xcat, 256, Bc, 128, fea_out, 128,
                                            N, 128, 256, cb, feab);
  };

  const float* xd = (const float*)d_in[0];
  const float* xr = (const float*)d_in[1];
  const int* eid = (const int*)d_in[2];
  const int* eir = (const int*)d_in[3];
  const float* ewd = (const float*)d_in[4];
  const float* ewr = (const float*)d_in[5];

  branch(xd, eid, ewd,
         (const float*)d_in[6], (const float*)d_in[7], (const float*)d_in[8], (const float*)d_in[9],
         (const float*)d_in[10], (const float*)d_in[11], (const float*)d_in[12],
         (const float*)d_in[13], (const float*)d_in[14], (const float*)d_in[15],
         (const float*)d_in[16], (const float*)d_in[17],
         fea_dis, disb);
  branch(xr, eir, ewr,
         (const float*)d_in[18], (const float*)d_in[19], (const float*)d_in[20], (const float*)d_in[21],
         (const float*)d_in[22], (const float*)d_in[23], (const float*)d_in[24],
         (const float*)d_in[25], (const float*)d_in[26], (const float*)d_in[27],
         (const float*)d_in[28], (const float*)d_in[29],
         fea_drug, drugb);

  k_final<<<dim3(47, 47), 256, 0, stream>>>(drugb, disb, out);
}

// Round 2
// 282.786 us; speedup vs baseline: 1.8149x; 1.8149x over previous
//
#include <hip/hip_runtime.h>

#define NN 6000
#define EE 144000

typedef __attribute__((ext_vector_type(8))) short bf16x8;
typedef __attribute__((ext_vector_type(4))) float f32x4;

__device__ __forceinline__ unsigned short f2bf(float f) {
  unsigned int u = __float_as_uint(f);
  u += 0x7FFF + ((u >> 16) & 1);
  return (unsigned short)(u >> 16);
}
__device__ __forceinline__ float bf2f(unsigned short u) {
  return __uint_as_float(((unsigned int)u) << 16);
}
__device__ __forceinline__ float lexp(float v) {
  v = v > 0.f ? v : 0.2f * v;   // leaky_relu(0.2) then exp
  return __expf(v);
}

// ---- prep: weight repacks + x->bf16 (both branches, one launch) ----------
// BcatT[b][L][j(640)][k(128)] = (j<512 ? gW[k,j] : WL[k,j-512])   (bf16)
// cWb[b][o(128)][k(256)] = cW[o,k]                                 (bf16)
// xb[b][n][k] = x[n,k]                                             (bf16)
__global__ void k_prep(const float* __restrict__ gW0, const float* __restrict__ gW1,
                       const float* __restrict__ g1W0, const float* __restrict__ g1W1,
                       const float* __restrict__ g2W0, const float* __restrict__ g2W1,
                       const float* __restrict__ cW0, const float* __restrict__ cW1,
                       const float* __restrict__ x0, const float* __restrict__ x1,
                       unsigned short* __restrict__ BcatT,
                       unsigned short* __restrict__ cWb,
                       unsigned short* __restrict__ xb) {
  int idx = blockIdx.x * 256 + threadIdx.x;
  if (idx < 327680) {
    int b = idx / 163840;
    int r = idx % 163840;
    int L = r / 81920;
    int r2 = r % 81920;
    int j = r2 / 128, k = r2 % 128;
    const float* gW = b ? gW1 : gW0;
    const float* WL = L ? (b ? g2W1 : g2W0) : (b ? g1W1 : g1W0);
    float v = (j < 512) ? gW[k * 512 + j] : WL[k * 128 + (j - 512)];
    BcatT[idx] = f2bf(v);
  } else if (idx < 393216) {
    int i2 = idx - 327680;
    int b = i2 >> 15;
    int ok = i2 & 32767;
    cWb[i2] = f2bf((b ? cW1 : cW0)[ok]);
  } else {
    int i3 = idx - 393216;   // < 1,536,000
    int b = i3 >= 768000;
    int local = i3 - b * 768000;
    xb[i3] = f2bf((b ? x1 : x0)[local]);
  }
}

// ---- degrees / counts / mean(ew) -----------------------------------------
__global__ void k_deg(const int* __restrict__ ei0, const int* __restrict__ ei1,
                      const float* __restrict__ ew0, const float* __restrict__ ew1,
                      float* __restrict__ deg, int* __restrict__ cnt,
                      float* __restrict__ easum) {
  int b = blockIdx.y;
  int e = blockIdx.x * 256 + threadIdx.x;
  const int* ei = b ? ei1 : ei0;
  const float* ew = b ? ew1 : ew0;
  float w = 0.f;
  if (e < EE) {
    int c = ei[EE + e];
    w = ew[e];
    atomicAdd(deg + b * NN + c, w);
    atomicAdd(cnt + b * NN + c, 1);
  }
  __shared__ float red[256];
  red[threadIdx.x] = w;
  __syncthreads();
  for (int off = 128; off > 0; off >>= 1) {
    if (threadIdx.x < off) red[threadIdx.x] += red[threadIdx.x + off];
    __syncthreads();
  }
  if (threadIdx.x == 0) atomicAdd(easum + b, red[0]);
}

// ---- dinv + per-head edge-weight dots wd ---------------------------------
__global__ void k_dinv(const float* __restrict__ deg, float* __restrict__ dinv,
                       const float* __restrict__ We0, const float* __restrict__ We1,
                       const float* __restrict__ ae0, const float* __restrict__ ae1,
                       float* __restrict__ wd) {
  int i = blockIdx.x * 256 + threadIdx.x;
  if (i < 2 * NN) dinv[i] = rsqrtf(deg[i] + 1.0f);   // +1 = self-loop weight
  if (blockIdx.x < 2) {
    int b = blockIdx.x;
    const float* We = b ? We1 : We0;
    const float* ae = b ? ae1 : ae0;
    int t = threadIdx.x;
    int h = t >> 6, lane = t & 63;
    int f = h * 128 + lane * 2;
    float p = We[f] * ae[f] + We[f + 1] * ae[f + 1];
    for (int off = 32; off > 0; off >>= 1) p += __shfl_down(p, off);
    if (lane == 0) wd[b * 4 + h] = p;
  }
}

// ---- exclusive-scan of per-node counts -> CSR row ptr (1 block/branch) ---
__global__ __launch_bounds__(1024) void k_scan(const int* __restrict__ cnt,
                                               int* __restrict__ rp) {
  int b = blockIdx.x;
  const int* c = cnt + b * NN;
  int* r = rp + b * (NN + 1);
  __shared__ int wsum[16];
  __shared__ int carry;
  int t = threadIdx.x, lane = t & 63, wid = t >> 6;
  if (t == 0) { carry = 0; r[0] = 0; }
  __syncthreads();
  for (int base = 0; base < NN; base += 1024) {
    int v = (base + t < NN) ? c[base + t] : 0;
#pragma unroll
    for (int off = 1; off < 64; off <<= 1) {
      int u = __shfl_up(v, off);
      if (lane >= off) v += u;
    }
    if (lane == 63) wsum[wid] = v;
    __syncthreads();
    if (wid == 0) {
      int s = (lane < 16) ? wsum[lane] : 0;
#pragma unroll
      for (int off = 1; off < 16; off <<= 1) {
        int u = __shfl_up(s, off);
        if (lane >= off) s += u;
      }
      if (lane < 16) wsum[lane] = s;
    }
    __syncthreads();
    int add = carry + (wid ? wsum[wid - 1] : 0);
    if (base + t < NN) r[base + t + 1] = v + add;
    __syncthreads();
    if (t == 1023) carry = add + v;
    __syncthreads();
  }
}

// ---- counting-sort edges by target ---------------------------------------
__global__ void k_fill(const int* __restrict__ ei0, const int* __restrict__ ei1,
                       const float* __restrict__ ew0, const float* __restrict__ ew1,
                       const int* __restrict__ rp, int* __restrict__ cursor,
                       const float* __restrict__ dinv,
                       int* __restrict__ sr, float* __restrict__ snorm,
                       float* __restrict__ swt) {
  int b = blockIdx.y;
  int e = blockIdx.x * 256 + threadIdx.x;
  if (e >= EE) return;
  const int* ei = b ? ei1 : ei0;
  const float* ew = b ? ew1 : ew0;
  int r = ei[e], c = ei[EE + e];
  float w = ew[e];
  int pos = rp[b * (NN + 1) + c] + atomicAdd(cursor + b * NN + c, 1);
  size_t gp = (size_t)b * EE + pos;
  sr[gp] = r;
  snorm[gp] = dinv[b * NN + r] * w * dinv[b * NN + c];
  swt[gp] = w;
}

// ---- bf16 MFMA GEMM: C[M,N] = A[M,K] @ Bt[N,K]^T  (N%64==0, K%32==0) -----
__global__ __launch_bounds__(256) void k_mgemm(
    const unsigned short* __restrict__ A, int lda, long sA,
    const unsigned short* __restrict__ Bt, long sB,
    unsigned short* __restrict__ Cb, int ldc, long sC,
    float* __restrict__ Cf, long sCf,
    const float* __restrict__ bias0, const float* __restrict__ bias1,
    int M, int K) {
  int z = blockIdx.z;
  A += (size_t)z * sA;
  Bt += (size_t)z * sB;
  Cb += (size_t)z * sC;
  if (Cf) Cf += (size_t)z * sCf;
  const float* bias = z ? bias1 : bias0;

  int w = threadIdx.x >> 6;
  int lane = threadIdx.x & 63;
  int lr = lane & 15, lg = lane >> 4;
  int n0 = blockIdx.x * 64 + w * 16;
  int m0 = blockIdx.y * 64;
  f32x4 acc[4] = {};
  for (int ks = 0; ks < K; ks += 32) {
    int kc = ks + lg * 8;
    bf16x8 bfr = *reinterpret_cast<const bf16x8*>(Bt + (size_t)(n0 + lr) * K + kc);
    bf16x8 a[4];
#pragma unroll
    for (int mt = 0; mt < 4; ++mt) {
      int row = m0 + mt * 16 + lr;
      bf16x8 v = {};
      if (row < M) v = *reinterpret_cast<const bf16x8*>(A + (size_t)row * lda + kc);
      a[mt] = v;
    }
#pragma unroll
    for (int mt = 0; mt < 4; ++mt)
      acc[mt] = __builtin_amdgcn_mfma_f32_16x16x32_bf16(a[mt], bfr, acc[mt], 0, 0, 0);
  }
#pragma unroll
  for (int mt = 0; mt < 4; ++mt)
#pragma unroll
    for (int r = 0; r < 4; ++r) {
      int row = m0 + mt * 16 + lg * 4 + r;
      int col = n0 + lr;
      if (row < M) {
        float v = acc[mt][r] + (bias ? bias[col] : 0.f);
        Cb[(size_t)row * ldc + col] = f2bf(v);
        if (Cf) Cf[(size_t)row * ldc + col] = v;
      }
    }
}

// ---- per-node per-head attention pre-dots s,d (bf16 h) -------------------
__global__ __launch_bounds__(256) void k_sd(const unsigned short* __restrict__ hbuf,
                                            const float* __restrict__ as0,
                                            const float* __restrict__ as1,
                                            const float* __restrict__ ad0,
                                            const float* __restrict__ ad1,
                                            float* __restrict__ s, float* __restrict__ d) {
  int n = blockIdx.x;
  int b = n >= NN;
  const float* as = b ? as1 : as0;
  const float* ad = b ? ad1 : ad0;
  int t = threadIdx.x;
  int h = t >> 6, lane = t & 63;
  int idx2 = h * 128 + lane * 2;
  unsigned int u = *reinterpret_cast<const unsigned int*>(hbuf + (size_t)n * 640 + idx2);
  float e0 = bf2f((unsigned short)(u & 0xffff));
  float e1 = bf2f((unsigned short)(u >> 16));
  float ps = e0 * as[idx2] + e1 * as[idx2 + 1];
  float pd = e0 * ad[idx2] + e1 * ad[idx2 + 1];
  for (int off = 32; off > 0; off >>= 1) {
    ps += __shfl_down(ps, off);
    pd += __shfl_down(pd, off);
  }
  if (lane == 0) { s[n * 4 + h] = ps; d[n * 4 + h] = pd; }
}

// ---- fused GCN+GAT aggregate + combine + relu + bf16 store ---------------
__global__ __launch_bounds__(128) void k_agg(
    const int* __restrict__ rp, const int* __restrict__ sr,
    const float* __restrict__ snorm, const float* __restrict__ swt,
    const unsigned short* __restrict__ hbuf,
    const float* __restrict__ s, const float* __restrict__ d,
    const float* __restrict__ wd, const float* __restrict__ easum,
    const float* __restrict__ dinv,
    const float* __restrict__ gcnb0, const float* __restrict__ gcnb1,
    const float* __restrict__ gatb0, const float* __restrict__ gatb1,
    unsigned short* __restrict__ xcat, int colOff) {
  int n = blockIdx.x;
  int b = n >= NN;
  int nn = n - b * NN;
  int c = threadIdx.x;
  float eam = easum[b] * (1.f / (float)EE);
  float4 w4 = *reinterpret_cast<const float4*>(wd + b * 4);
  float4 sn = *reinterpret_cast<const float4*>(s + (size_t)n * 4);
  float4 dn = *reinterpret_cast<const float4*>(d + (size_t)n * 4);
  // self-loop (r = nn, edge attr = mean(ew), gcn w = 1)
  float p0 = lexp(sn.x + dn.x + eam * w4.x);
  float p1 = lexp(sn.y + dn.y + eam * w4.y);
  float p2 = lexp(sn.z + dn.z + eam * w4.z);
  float p3 = lexp(sn.w + dn.w + eam * w4.w);
  const unsigned short* hn = hbuf + (size_t)n * 640;
  float a0 = p0 * bf2f(hn[c]);
  float a1 = p1 * bf2f(hn[128 + c]);
  float a2 = p2 * bf2f(hn[256 + c]);
  float a3 = p3 * bf2f(hn[384 + c]);
  float dv = dinv[b * NN + nn];
  float ag = dv * dv * bf2f(hn[512 + c]);
  float d0 = p0, d1 = p1, d2 = p2, d3 = p3;

  __shared__ int lr_[128];
  __shared__ float lnorm[128];
  __shared__ float lp[128][4];

  const int* rpb = rp + b * (NN + 1);
  int beg = rpb[nn], end = rpb[nn + 1];
  const unsigned short* hb = hbuf + (size_t)b * NN * 640;
  for (int ch = beg; ch < end; ch += 128) {
    int m = min(128, end - ch);
    __syncthreads();
    if (c < m) {
      size_t pos = (size_t)b * EE + ch + c;
      int r = sr[pos];
      float4 sv = *reinterpret_cast<const float4*>(s + ((size_t)b * NN + r) * 4);
      float w = swt[pos];
      lr_[c] = r;
      lnorm[c] = snorm[pos];
      lp[c][0] = lexp(sv.x + dn.x + w * w4.x);
      lp[c][1] = lexp(sv.y + dn.y + w * w4.y);
      lp[c][2] = lexp(sv.z + dn.z + w * w4.z);
      lp[c][3] = lexp(sv.w + dn.w + w * w4.w);
    }
    __syncthreads();
    for (int i = 0; i < m; ++i) {
      int r = lr_[i];
      const unsigned short* hr = hb + (size_t)r * 640;
      float4 pv = *reinterpret_cast<const float4*>(lp[i]);
      float nr = lnorm[i];
      a0 += pv.x * bf2f(hr[c]);
      a1 += pv.y * bf2f(hr[128 + c]);
      a2 += pv.z * bf2f(hr[256 + c]);
      a3 += pv.w * bf2f(hr[384 + c]);
      ag += nr * bf2f(hr[512 + c]);
      d0 += pv.x; d1 += pv.y; d2 += pv.z; d3 += pv.w;
    }
  }
  float gat = 0.25f * (a0 / d0 + a1 / d1 + a2 / d2 + a3 / d3);
  float gcnb = (b ? gcnb1 : gcnb0)[c];
  float gatb = (b ? gatb1 : gatb0)[c];
  float l = ag + gcnb + gat + gatb;
  xcat[(size_t)n * 256 + colOff + c] = f2bf(fmaxf(0.5f * l, 0.f));
}

// ---- final MFMA: C[i,j] = sum_k drug[i,k]*dis[j,k] -----------------------
__global__ __launch_bounds__(256) void k_final(const unsigned short* __restrict__ Ab,
                                               const unsigned short* __restrict__ Bb,
                                               float* __restrict__ C) {
  int wave = threadIdx.x >> 6;
  int lane = threadIdx.x & 63;
  int wm = wave >> 1, wn = wave & 1;
  int m0 = blockIdx.y * 128 + wm * 64;
  int n0 = blockIdx.x * 128 + wn * 64;
  int lr = lane & 15;
  int lg = lane >> 4;
  f32x4 acc[4][4] = {};
#pragma unroll
  for (int ks = 0; ks < 4; ++ks) {
    int kcol = ks * 32 + lg * 8;
    bf16x8 a[4], b[4];
#pragma unroll
    for (int mt = 0; mt < 4; ++mt) {
      int row = m0 + mt * 16 + lr;
      bf16x8 v = {};
      if (row < NN) v = *reinterpret_cast<const bf16x8*>(Ab + (size_t)row * 128 + kcol);
      a[mt] = v;
    }
#pragma unroll
    for (int nt = 0; nt < 4; ++nt) {
      int rb = n0 + nt * 16 + lr;
      bf16x8 v = {};
      if (rb < NN) v = *reinterpret_cast<const bf16x8*>(Bb + (size_t)rb * 128 + kcol);
      b[nt] = v;
    }
#pragma unroll
    for (int mt = 0; mt < 4; ++mt)
#pragma unroll
      for (int nt = 0; nt < 4; ++nt)
        acc[mt][nt] = __builtin_amdgcn_mfma_f32_16x16x32_bf16(a[mt], b[nt], acc[mt][nt], 0, 0, 0);
  }
#pragma unroll
  for (int mt = 0; mt < 4; ++mt)
#pragma unroll
    for (int nt = 0; nt < 4; ++nt)
#pragma unroll
      for (int r = 0; r < 4; ++r) {
        int row = m0 + mt * 16 + lg * 4 + r;
        int col = n0 + nt * 16 + lr;
        if (row < NN && col < NN) C[(size_t)row * NN + col] = acc[mt][nt][r];
      }
}

// ==========================================================================
extern "C" void kernel_launch(void* const* d_in, const int* in_sizes, int n_in,
                              void* d_out, int out_size, void* d_ws, size_t ws_size,
                              hipStream_t stream) {
  char* wsp = (char*)d_ws;
  size_t off = 0;
  auto alloc = [&](size_t bytes) -> char* {
    char* ptr = wsp + off;
    off += (bytes + 255) & ~(size_t)255;
    return ptr;
  };
  // zero-region (one memset): deg, cnt, cursor, easum
  float* deg = (float*)alloc(2 * NN * 4);
  int* cnt = (int*)alloc(2 * NN * 4);
  int* cursor = (int*)alloc(2 * NN * 4);
  float* easum = (float*)alloc(256);
  size_t zero_bytes = (size_t)((char*)easum - (char*)deg) + 256;
  float* dinv = (float*)alloc(2 * NN * 4);
  int* rp = (int*)alloc(2 * (NN + 1) * 4);
  float* wd = (float*)alloc(256);
  int* sr = (int*)alloc((size_t)2 * EE * 4);
  float* snorm = (float*)alloc((size_t)2 * EE * 4);
  float* swt = (float*)alloc((size_t)2 * EE * 4);
  unsigned short* BcatT = (unsigned short*)alloc((size_t)327680 * 2);
  unsigned short* cWb = (unsigned short*)alloc((size_t)65536 * 2);
  unsigned short* xb = (unsigned short*)alloc((size_t)2 * NN * 128 * 2);
  unsigned short* hbuf = (unsigned short*)alloc((size_t)2 * NN * 640 * 2);
  float* sbuf = (float*)alloc((size_t)2 * NN * 4 * 4);
  float* dbuf = (float*)alloc((size_t)2 * NN * 4 * 4);
  unsigned short* xcat = (unsigned short*)alloc((size_t)2 * NN * 256 * 2);
  unsigned short* feab = (unsigned short*)alloc((size_t)2 * NN * 128 * 2);
  if (off > ws_size) return;  // fail loud (wrong output) rather than corrupt

  float* out = (float*)d_out;
  float* fea_dis = out + (size_t)36000000;          // b=0 slot
  // fea_drug = fea_dis + 768000                    // b=1 slot (contiguous)

  const float* x0 = (const float*)d_in[0];
  const float* x1 = (const float*)d_in[1];
  const int* ei0 = (const int*)d_in[2];
  const int* ei1 = (const int*)d_in[3];
  const float* ew0 = (const float*)d_in[4];
  const float* ew1 = (const float*)d_in[5];
  // dis params: 6..17, drug params: 18..29
  const float* g1W0 = (const float*)d_in[6];  const float* g1b0 = (const float*)d_in[7];
  const float* g2W0 = (const float*)d_in[8];  const float* g2b0 = (const float*)d_in[9];
  const float* gW0 = (const float*)d_in[10];  const float* gas0 = (const float*)d_in[11];
  const float* gad0 = (const float*)d_in[12]; const float* gWe0 = (const float*)d_in[13];
  const float* gae0 = (const float*)d_in[14]; const float* gb0 = (const float*)d_in[15];
  const float* cW0 = (const float*)d_in[16];  const float* cb0 = (const float*)d_in[17];
  const float* g1W1 = (const float*)d_in[18]; const float* g1b1 = (const float*)d_in[19];
  const float* g2W1 = (const float*)d_in[20]; const float* g2b1 = (const float*)d_in[21];
  const float* gW1 = (const float*)d_in[22];  const float* gas1 = (const float*)d_in[23];
  const float* gad1 = (const float*)d_in[24]; const float* gWe1 = (const float*)d_in[25];
  const float* gae1 = (const float*)d_in[26]; const float* gb1 = (const float*)d_in[27];
  const float* cW1 = (const float*)d_in[28];  const float* cb1 = (const float*)d_in[29];

  hipMemsetAsync(deg, 0, zero_bytes, stream);
  k_prep<<<7536, 256, 0, stream>>>(gW0, gW1, g1W0, g1W1, g2W0, g2W1, cW0, cW1,
                                   x0, x1, BcatT, cWb, xb);
  k_deg<<<dim3(563, 2), 256, 0, stream>>>(ei0, ei1, ew0, ew1, deg, cnt, easum);
  k_dinv<<<47, 256, 0, stream>>>(deg, dinv, gWe0, gWe1, gae0, gae1, wd);
  k_scan<<<2, 1024, 0, stream>>>(cnt, rp);
  k_fill<<<dim3(563, 2), 256, 0, stream>>>(ei0, ei1, ew0, ew1, rp, cursor, dinv,
                                           sr, snorm, swt);
  // layer 1: hbuf = xb @ BcatT(L0)^T
  k_mgemm<<<dim3(10, 94, 2), 256, 0, stream>>>(
      xb, 128, (long)NN * 128, BcatT, 163840,
      hbuf, 640, (long)NN * 640, nullptr, 0, nullptr, nullptr, NN, 128);
  k_sd<<<2 * NN, 256, 0, stream>>>(hbuf, gas0, gas1, gad0, gad1, sbuf, dbuf);
  k_agg<<<2 * NN, 128, 0, stream>>>(rp, sr, snorm, swt, hbuf, sbuf, dbuf, wd,
                                    easum, dinv, g1b0, g1b1, gb0, gb1, xcat, 0);
  // layer 2: hbuf = x1cols(xcat[:, :128]) @ BcatT(L1)^T
  k_mgemm<<<dim3(10, 94, 2), 256, 0, stream>>>(
      xcat, 256, (long)NN * 256, BcatT + 81920, 163840,
      hbuf, 640, (long)NN * 640, nullptr, 0, nullptr, nullptr, NN, 128);
  k_sd<<<2 * NN, 256, 0, stream>>>(hbuf, gas0, gas1, gad0, gad1, sbuf, dbuf);
  k_agg<<<2 * NN, 128, 0, stream>>>(rp, sr, snorm, swt, hbuf, sbuf, dbuf, wd,
                                    easum, dinv, g2b0, g2b1, gb0, gb1, xcat, 128);
  // fea = xcat @ cWb^T + cb  (fp32 to d_out, bf16 copy for final MFMA)
  k_mgemm<<<dim3(2, 94, 2), 256, 0, stream>>>(
      xcat, 256, (long)NN * 256, cWb, 32768,
      feab, 128, (long)NN * 128, fea_dis, (long)NN * 128, cb0, cb1, NN, 256);
  // out = drug_fea @ dis_fea^T
  k_final<<<dim3(47, 47), 256, 0, stream>>>(feab + (size_t)NN * 128, feab, out);
}